// Round 9
// baseline (428.856 us; speedup 1.0000x reference)
//
#include <hip/hip_runtime.h>
#include <hip/hip_cooperative_groups.h>
#include <hip/hip_bf16.h>
#include <math.h>

namespace cg = cooperative_groups;

typedef __bf16 bf16;
typedef __bf16 bf16x8 __attribute__((ext_vector_type(8)));
typedef __bf16 bf16x4 __attribute__((ext_vector_type(4)));
typedef float floatx4 __attribute__((ext_vector_type(4)));

typedef const __attribute__((address_space(1))) void* gas_t;
typedef __attribute__((address_space(3))) void* las_t;

#define NPIX 4096
#define DCH 256

// ---------------- workspace layout (bytes), ~124 MB of 256 MiB ----------------
#define OFF_XB   ((size_t)0)            // bf16 [8192][256]      4 MB
#define OFF_WB   ((size_t)4194304)      // bf16 [768][256]       384 KB
#define OFF_Q    ((size_t)4587520)      // bf16 [8192][256]      4 MB
#define OFF_K    ((size_t)8781824)      // bf16 [8192][256]      4 MB
#define OFF_V    ((size_t)12976128)     // bf16 [8192][256]      4 MB
#define OFF_E    ((size_t)17170432)     // bf16 [2][4096][4096]  64 MB
#define OFF_VPP  ((size_t)84279296)     // bf16 [2][256][4096]   4 MB
#define OFF_RP   ((size_t)88473600)     // f32  [2][32][4096]    1 MB
#define OFF_CP   ((size_t)89522176)     // f32  [2][32][4096]    1 MB
#define OFF_PART ((size_t)90570752)     // f32  [2][4][256][4096] 32 MB
#define OFF_EU   ((size_t)124125184)    // f32  [2][4096]        32 KB  (exp(u) per row)

struct Params {
  const float* x; const float* W; const float* bias;
  bf16* xb; bf16* wb; bf16* qb; bf16* kb; bf16* vb;
  bf16* E; bf16* vppT; float* rp; float* cp; float* part;
  float* euG; float* outp; float logm;
};

// EXACTLY 32768 B so 2 blocks/CU fit even under a 64 KiB LDS accounting pool.
union Smem {
  struct { bf16 a[8192]; bf16 b[8192]; } g;        // 32768 B (GEMM tiles)
  struct { float ts[64][65]; float ef[64]; } tp;   // 16896 B (transpose phases)
  float f[8192];                                   // float view for misc reuse
};

// m97-style staging: global->LDS DMA, 16B/lane, XOR swizzle on the GLOBAL side.
// LDS[row][seg] = global[row][seg ^ (row&7)].
__device__ __forceinline__ void stage_tile(const bf16* __restrict__ g0, size_t rstride,
                                           bf16* lds, int t) {
  const int wbase = (t >> 6) << 6;
#pragma unroll
  for (int i = 0; i < 4; i++) {
    int slot = i * 256 + t;
    int row = slot >> 3, seg = slot & 7;
    const bf16* g = g0 + (size_t)row * rstride + ((seg ^ (row & 7)) << 3);
    bf16* l = lds + (size_t)(i * 256 + wbase) * 8;
    __builtin_amdgcn_global_load_lds((gas_t)g, (las_t)l, 16, 0, 0);
  }
}

// ============ P0a: transpose x [b][c][n] -> xb [b*4096+n][c] (bf16); vb < 512 ============
__device__ void do_transpose(int vb, int t, Smem& sm, const float* x, bf16* xb) {
  const int b = vb >> 8, n0 = (vb & 63) * 64, c0 = ((vb >> 6) & 3) * 64;
  const float* xp = x + ((size_t)b * DCH + c0) * NPIX + n0;
  for (int i = 0; i < 4; i++) {
    int slot = t + i * 256;
    int c = slot >> 4, nq = (slot & 15) * 4;
    float4 v = *(const float4*)(xp + (size_t)c * NPIX + nq);
    sm.tp.ts[c][nq + 0] = v.x; sm.tp.ts[c][nq + 1] = v.y;
    sm.tp.ts[c][nq + 2] = v.z; sm.tp.ts[c][nq + 3] = v.w;
  }
  __syncthreads();
  for (int i = 0; i < 2; i++) {
    int slot = t + i * 256;
    int n = slot >> 3, cq = (slot & 7) * 8;
    bf16x8 pk;
    for (int j = 0; j < 8; j++) pk[j] = (bf16)sm.tp.ts[cq + j][n];
    *(bf16x8*)(xb + ((size_t)b * NPIX + n0 + n) * DCH + c0 + cq) = pk;
  }
  __syncthreads();
}

// ============ P1: 1x1 conv as bf16 MFMA GEMM; vb < 384 ============
__device__ void do_conv(int vb, int t, Smem& sm, const bf16* xb, const bf16* wb,
                        const float* bias, bf16* qb, bf16* kb, bf16* vbuf) {
  const int n0 = (vb & 63) * 128;
  const int o0 = (vb >> 6) * 128;
  const int lane = t & 63, wave = t >> 6;
  const int wm = wave >> 1, wn = wave & 1;
  const int l15 = lane & 15, quad = lane >> 4;
  const int l7 = l15 & 7;

  floatx4 acc[4][4];
  for (int i=0;i<4;i++) for (int j=0;j<4;j++) for (int r=0;r<4;r++) acc[i][j][r] = 0.f;

  for (int k0 = 0; k0 < DCH; k0 += 64) {
    stage_tile(wb + (size_t)o0 * DCH + k0, DCH, sm.g.a, t);
    stage_tile(xb + (size_t)n0 * DCH + k0, DCH, sm.g.b, t);
    __syncthreads();
    for (int kk = 0; kk < 2; kk++) {
      bf16x8 af[4], bfr[4];
      int sw = ((kk * 4 + quad) ^ l7) * 8;
      for (int f = 0; f < 4; f++)
        af[f]  = *(const bf16x8*)&sm.g.a[(wm*64 + f*16 + l15)*64 + sw];
      for (int f = 0; f < 4; f++)
        bfr[f] = *(const bf16x8*)&sm.g.b[(wn*64 + f*16 + l15)*64 + sw];
      for (int fm = 0; fm < 4; fm++)
        for (int fn = 0; fn < 4; fn++)
          acc[fm][fn] = __builtin_amdgcn_mfma_f32_16x16x32_bf16(af[fm], bfr[fn], acc[fm][fn], 0, 0, 0);
    }
    __syncthreads();
  }

  const float scale = (o0 < 512) ? 0.25f : 1.0f;
  bf16* dst; int od;
  if (o0 < 256)      { dst = qb; od = o0; }
  else if (o0 < 512) { dst = kb; od = o0 - 256; }
  else               { dst = vbuf; od = o0 - 512; }

  for (int fm = 0; fm < 4; fm++)
    for (int fn = 0; fn < 4; fn++) {
      int o_l = wm*64 + fm*16 + quad*4;
      int n_g = n0 + wn*64 + fn*16 + l15;
      bf16x4 pk;
      for (int r = 0; r < 4; r++)
        pk[r] = (bf16)((acc[fm][fn][r] + bias[o0 + o_l + r]) * scale);
      *(bf16x4*)(dst + (size_t)n_g * DCH + od + o_l) = pk;
    }
}

// ============ P2: pass A — E = exp(q k^T); rowpart partials; vb < 2048 ============
__device__ void do_pass_a(int vb, int t, Smem& sm, const bf16* qb0, const bf16* kb0,
                          bf16* E0, float* rowpartG) {
  const int b = vb >> 10;
  const int m_tile = vb & 31, n_tile = (vb >> 5) & 31;
  const bf16* qb = qb0 + (size_t)b * NPIX * DCH;
  const bf16* kb = kb0 + (size_t)b * NPIX * DCH;
  bf16* E = E0 + (size_t)b * NPIX * NPIX;
  float* rp = rowpartG + ((size_t)b * 32 + m_tile) * NPIX;
  const int m0 = m_tile * 128, n0 = n_tile * 128;
  const int lane = t & 63, wave = t >> 6;
  const int wm = wave >> 1, wn = wave & 1;
  const int l15 = lane & 15, quad = lane >> 4;
  const int l7 = l15 & 7;

  floatx4 acc[4][4];
  for (int i=0;i<4;i++) for (int j=0;j<4;j++) for (int r=0;r<4;r++) acc[i][j][r] = 0.f;

  for (int k0 = 0; k0 < DCH; k0 += 64) {
    stage_tile(kb + (size_t)m0 * DCH + k0, DCH, sm.g.a, t);
    stage_tile(qb + (size_t)n0 * DCH + k0, DCH, sm.g.b, t);
    __syncthreads();
    for (int kk = 0; kk < 2; kk++) {
      bf16x8 af[4], bfr[4];
      int sw = ((kk * 4 + quad) ^ l7) * 8;
      for (int f = 0; f < 4; f++)
        af[f]  = *(const bf16x8*)&sm.g.a[(wm*64 + f*16 + l15)*64 + sw];
      for (int f = 0; f < 4; f++)
        bfr[f] = *(const bf16x8*)&sm.g.b[(wn*64 + f*16 + l15)*64 + sw];
      for (int fm = 0; fm < 4; fm++)
        for (int fn = 0; fn < 4; fn++)
          acc[fm][fn] = __builtin_amdgcn_mfma_f32_16x16x32_bf16(af[fm], bfr[fn], acc[fm][fn], 0, 0, 0);
    }
    __syncthreads();
  }

  // tiles are dead; reuse the first 512 B of LDS as the cross-wave rowpart buffer
  float* rowpart = sm.f;
  if (t < 128) rowpart[t] = 0.f;
  __syncthreads();

  float rsum[4] = {0.f, 0.f, 0.f, 0.f};
  for (int fm = 0; fm < 4; fm++)
    for (int fn = 0; fn < 4; fn++) {
      int n_g = n0 + wn*64 + fn*16 + l15;
      int m_g = m0 + wm*64 + fm*16 + quad*4;
      bf16x4 pk;
      float s = 0.f;
      for (int r = 0; r < 4; r++) {
        float e = __expf(acc[fm][fn][r]);
        pk[r] = (bf16)e;
        s += e;
      }
      *(bf16x4*)(E + (size_t)n_g * NPIX + m_g) = pk;
      rsum[fn] += s;
    }
  for (int fn = 0; fn < 4; fn++) {
    float s = rsum[fn];
    s += __shfl_xor(s, 16);
    s += __shfl_xor(s, 32);
    if (quad == 0) atomicAdd(&rowpart[wn*64 + fn*16 + l15], s);
  }
  __syncthreads();
  if (t < 128) rp[n0 + t] = rowpart[t];
  __syncthreads();
}

// ============ P3: colpart partials + store eu[b][n]; vb < 256 ============
__device__ void do_col(int vb, int t, Smem& sm, const bf16* E0, const float* rowpartG,
                       float* colpartG, float* euG, float logm) {
  const int b = vb >> 7;
  const int xg = vb & 3, yg = (vb >> 2) & 31;
  const bf16* E = E0 + (size_t)b * NPIX * NPIX;
  const float* rp = rowpartG + (size_t)b * 32 * NPIX;
  float* cp = colpartG + ((size_t)b * 32 + yg) * NPIX;
  const int col = xg * 1024 + t * 4;
  const int nbase = yg * 128;
  if (t < 128) {
    float s = 0.f;
    for (int mi = 0; mi < 32; mi++) s += rp[(size_t)mi * NPIX + nbase + t];
    float e = __expf(logm - __logf(s));
    sm.f[t] = e;
    if (xg == 0) euG[b * NPIX + nbase + t] = e;   // publish exp(u) once per n
  }
  __syncthreads();
  float a0 = 0.f, a1 = 0.f, a2 = 0.f, a3 = 0.f;
  for (int r = 0; r < 128; r++) {
    float eu = sm.f[r];
    bf16x4 ev = *(const bf16x4*)(E + (size_t)(nbase + r) * NPIX + col);
    a0 += eu * (float)ev[0];
    a1 += eu * (float)ev[1];
    a2 += eu * (float)ev[2];
    a3 += eu * (float)ev[3];
  }
  float4 o = {a0, a1, a2, a3};
  *(float4*)(cp + col) = o;
  __syncthreads();
}

// ============ P4: v''T[d][m] = exp(vpot[m]) * v[m][d]; vb < 512 ============
__device__ void do_vpp(int vb, int t, Smem& sm, const bf16* vb0, const float* colpartG,
                       bf16* vppT0, float logm) {
  const int b = vb >> 8;
  const int m0 = (vb & 63) * 64, d0 = ((vb >> 6) & 3) * 64;
  const bf16* vbuf = vb0 + (size_t)b * NPIX * DCH;
  const float* cp = colpartG + (size_t)b * 32 * NPIX;
  bf16* vppT = vppT0 + (size_t)b * DCH * NPIX;
  if (t < 64) {
    float s = 0.f;
    for (int g = 0; g < 32; g++) s += cp[(size_t)g * NPIX + m0 + t];
    sm.tp.ef[t] = __expf(logm - __logf(s));
  }
  __syncthreads();
  for (int i = 0; i < 2; i++) {
    int slot = t + i * 256;
    int m = slot >> 3, dq = (slot & 7) * 8;
    bf16x8 v = *(const bf16x8*)(vbuf + (size_t)(m0 + m) * DCH + d0 + dq);
    float s = sm.tp.ef[m];
    for (int j = 0; j < 8; j++) sm.tp.ts[dq + j][m] = s * (float)v[j];
  }
  __syncthreads();
  for (int i = 0; i < 2; i++) {
    int slot = t + i * 256;
    int d = slot >> 3, mq = (slot & 7) * 8;
    bf16x8 pk;
    for (int j = 0; j < 8; j++) pk[j] = (bf16)sm.tp.ts[d][mq + j];
    *(bf16x8*)(vppT + (size_t)(d0 + d) * NPIX + m0 + mq) = pk;
  }
  __syncthreads();
}

// ============ P5: pass C — part[b][kc][d][n] = eu[n] * (E_chunk @ v'')[n][d]; vb < 512 ============
__device__ void do_pass_c(int vb, int t, Smem& sm, const bf16* E0, const bf16* vppT0,
                          const float* euG, float* part0) {
  const int z = vb >> 6;
  const int b = z >> 2, kc = z & 3;
  const int n0 = (vb & 31) * 128;
  const int d0 = ((vb >> 5) & 1) * 128;
  const bf16* E = E0 + (size_t)b * NPIX * NPIX;
  const bf16* vppT = vppT0 + (size_t)b * DCH * NPIX;
  float* part = part0 + (size_t)(b * 4 + kc) * DCH * NPIX;
  const int mstart = kc * 1024;
  const int lane = t & 63, wave = t >> 6;
  const int wn = wave >> 1, wd = wave & 1;
  const int l15 = lane & 15, quad = lane >> 4;
  const int l7 = l15 & 7;

  floatx4 acc[4][4];
  for (int i=0;i<4;i++) for (int j=0;j<4;j++) for (int r=0;r<4;r++) acc[i][j][r] = 0.f;

  for (int k0 = mstart; k0 < mstart + 1024; k0 += 64) {
    stage_tile(E + (size_t)n0 * NPIX + k0, NPIX, sm.g.a, t);
    stage_tile(vppT + (size_t)d0 * NPIX + k0, NPIX, sm.g.b, t);
    __syncthreads();
    for (int kk = 0; kk < 2; kk++) {
      bf16x8 af[4], bfr[4];
      int sw = ((kk * 4 + quad) ^ l7) * 8;
      for (int f = 0; f < 4; f++)
        af[f]  = *(const bf16x8*)&sm.g.a[(wn*64 + f*16 + l15)*64 + sw];
      for (int f = 0; f < 4; f++)
        bfr[f] = *(const bf16x8*)&sm.g.b[(wd*64 + f*16 + l15)*64 + sw];
      for (int fn = 0; fn < 4; fn++)
        for (int fd = 0; fd < 4; fd++)
          acc[fn][fd] = __builtin_amdgcn_mfma_f32_16x16x32_bf16(af[fn], bfr[fd], acc[fn][fd], 0, 0, 0);
    }
    __syncthreads();
  }

  for (int fn = 0; fn < 4; fn++)
    for (int fd = 0; fd < 4; fd++) {
      int d_g = d0 + wd*64 + fd*16 + l15;
      int n_l = wn*64 + fn*16 + quad*4;
      const float* eup = euG + b * NPIX + n0 + n_l;
      float4 o;
      o.x = acc[fn][fd][0] * eup[0];
      o.y = acc[fn][fd][1] * eup[1];
      o.z = acc[fn][fd][2] * eup[2];
      o.w = acc[fn][fd][3] * eup[3];
      *(float4*)(part + (size_t)d_g * NPIX + n0 + n_l) = o;
    }
}

// ============ P6: reduce split-K partials; vb < 2048 ============
__device__ void do_reduce(int vb, int t, const float* part, float* outp) {
  size_t i4 = ((size_t)vb * 256 + t) * 4;
  size_t b = i4 >> 20;
  size_t off = i4 & (size_t)1048575;
  const float* p = part + b * 4 * (size_t)1048576 + off;
  float4 a = *(const float4*)(p);
  float4 bq = *(const float4*)(p + (size_t)1048576);
  float4 c = *(const float4*)(p + (size_t)2097152);
  float4 d = *(const float4*)(p + (size_t)3145728);
  float4 s = { a.x+bq.x+c.x+d.x, a.y+bq.y+c.y+d.y, a.z+bq.z+c.z+d.z, a.w+bq.w+c.w+d.w };
  *(float4*)(outp + i4) = s;
}

// ============ Mega kernel: all phases, one cooperative launch, grid-stride ============
__global__ __launch_bounds__(256, 2) void mega(Params p) {
  __shared__ Smem sm;
  cg::grid_group grid = cg::this_grid();
  const int bid = blockIdx.x;
  const int G = gridDim.x;
  const int t = threadIdx.x;

  // P0: transpose x (512) + convert W (192)
  for (int vb = bid; vb < 704; vb += G) {
    if (vb < 512) {
      do_transpose(vb, t, sm, p.x, p.xb);
    } else {
      int i = (vb - 512) * 256 + t;
      if (i < 49152) {
        float4 v = *(const float4*)(p.W + (size_t)i * 4);
        bf16x4 pk = { (bf16)v.x, (bf16)v.y, (bf16)v.z, (bf16)v.w };
        *(bf16x4*)(p.wb + (size_t)i * 4) = pk;
      }
    }
  }
  grid.sync();

  // P1: conv (384)
  for (int vb = bid; vb < 384; vb += G)
    do_conv(vb, t, sm, p.xb, p.wb, p.bias, p.qb, p.kb, p.vb);
  grid.sync();

  // P2: pass A (2048)
  for (int vb = bid; vb < 2048; vb += G)
    do_pass_a(vb, t, sm, p.qb, p.kb, p.E, p.rp);
  grid.sync();

  // P3: col pass (256)
  for (int vb = bid; vb < 256; vb += G)
    do_col(vb, t, sm, p.E, p.rp, p.cp, p.euG, p.logm);
  grid.sync();

  // P4: vpp (512)
  for (int vb = bid; vb < 512; vb += G)
    do_vpp(vb, t, sm, p.vb, p.cp, p.vppT, p.logm);
  grid.sync();

  // P5: pass C (512)
  for (int vb = bid; vb < 512; vb += G)
    do_pass_c(vb, t, sm, p.E, p.vppT, p.euG, p.part);
  grid.sync();

  // P6: reduce (2048)
  for (int vb = bid; vb < 2048; vb += G)
    do_reduce(vb, t, p.part, p.outp);
}

extern "C" void kernel_launch(void* const* d_in, const int* in_sizes, int n_in,
                              void* d_out, int out_size, void* d_ws, size_t ws_size,
                              hipStream_t stream) {
  (void)in_sizes; (void)n_in; (void)out_size; (void)ws_size;
  char* ws = (char*)d_ws;

  Params p;
  p.x    = (const float*)d_in[0];
  p.W    = (const float*)d_in[1];
  p.bias = (const float*)d_in[2];
  p.xb   = (bf16*)(ws + OFF_XB);
  p.wb   = (bf16*)(ws + OFF_WB);
  p.qb   = (bf16*)(ws + OFF_Q);
  p.kb   = (bf16*)(ws + OFF_K);
  p.vb   = (bf16*)(ws + OFF_V);
  p.E    = (bf16*)(ws + OFF_E);
  p.vppT = (bf16*)(ws + OFF_VPP);
  p.rp   = (float*)(ws + OFF_RP);
  p.cp   = (float*)(ws + OFF_CP);
  p.part = (float*)(ws + OFF_PART);
  p.euG  = (float*)(ws + OFF_EU);
  p.outp = (float*)d_out;
  p.logm = logf(1.0f / 4096.0f + 1e-8f);

  // Size the cooperative grid from the runtime's own occupancy answer —
  // R8's 512-block launch was silently rejected (too large).
  int dev = 0;
  hipGetDevice(&dev);
  int cus = 256;
  hipDeviceGetAttribute(&cus, hipDeviceAttributeMultiprocessorCount, dev);
  int perCU = 0;
  if (hipOccupancyMaxActiveBlocksPerMultiprocessor(&perCU, (const void*)mega, 256, 0)
      != hipSuccess || perCU < 1)
    perCU = 1;
  int grid = perCU * cus;
  if (grid > 512) grid = 512;

  void* args[] = { &p };
  hipLaunchCooperativeKernel((const void*)mega, dim3(grid), dim3(256), args, 0, stream);
}

// Round 10
// 160.060 us; speedup vs baseline: 2.6793x; 2.6793x over previous
//
#include <hip/hip_runtime.h>
#include <hip/hip_bf16.h>
#include <math.h>

typedef __bf16 bf16;
typedef __bf16 bf16x8 __attribute__((ext_vector_type(8)));
typedef __bf16 bf16x4 __attribute__((ext_vector_type(4)));
typedef float floatx4 __attribute__((ext_vector_type(4)));

typedef const __attribute__((address_space(1))) void* gas_t;
typedef __attribute__((address_space(3))) void* las_t;

#define NPIX 4096
#define DCH 256

// ---------------- workspace layout (bytes), ~107 MB of 256 MiB ----------------
#define OFF_XB   ((size_t)0)            // bf16 [8192][256]      4 MB
#define OFF_WB   ((size_t)4194304)      // bf16 [768][256]       384 KB
#define OFF_Q    ((size_t)4587520)      // bf16 [8192][256]      4 MB
#define OFF_K    ((size_t)8781824)      // bf16 [8192][256]      4 MB
#define OFF_V    ((size_t)12976128)     // bf16 [8192][256]      4 MB
#define OFF_E    ((size_t)17170432)     // bf16 [2][4096][4096]  64 MB
#define OFF_VPP  ((size_t)84279296)     // bf16 [2][256][4096]   4 MB
#define OFF_RP   ((size_t)88473600)     // f32  [2][32][4096]    1 MB  (rowsum partials per m-tile)
#define OFF_CP   ((size_t)89522176)     // f32  [2][32][4096]    1 MB  (colsum partials per n-group)
#define OFF_PART ((size_t)90570752)     // bf16 [2][4][256][4096] 16 MB (split-K partials, bf16)

// m97-style staging: global->LDS DMA, 16B/lane, XOR swizzle applied on the GLOBAL side
// (LDS side must stay wave-uniform-base + lane*16). LDS[row][seg] = global[row][seg^(row&7)].
__device__ __forceinline__ void stage_tile(const bf16* __restrict__ g0, size_t rstride,
                                           bf16* lds, int t) {
  const int wbase = (t >> 6) << 6;
#pragma unroll
  for (int i = 0; i < 4; i++) {
    int slot = i * 256 + t;
    int row = slot >> 3, seg = slot & 7;
    const bf16* g = g0 + (size_t)row * rstride + ((seg ^ (row & 7)) << 3);
    bf16* l = lds + (size_t)(i * 256 + wbase) * 8;
    __builtin_amdgcn_global_load_lds((gas_t)g, (las_t)l, 16, 0, 0);
  }
}

// ============ K0: prep = transpose x to [n][c] bf16 (y<4) + convert W to bf16 (y==4) ============
__global__ __launch_bounds__(256) void prep(
    const float* __restrict__ x, const float* __restrict__ W,
    bf16* __restrict__ xb, bf16* __restrict__ wb)
{
  const int t = threadIdx.x;
  if (blockIdx.y == 4) {
    int gid = (blockIdx.z * 64 + blockIdx.x) * 256 + t;
    for (int i = gid; i < 49152; i += 32768) {
      float4 v = *(const float4*)(W + (size_t)i * 4);
      bf16x4 pk = { (bf16)v.x, (bf16)v.y, (bf16)v.z, (bf16)v.w };
      *(bf16x4*)(wb + (size_t)i * 4) = pk;
    }
    return;
  }
  __shared__ float ts[64][65];
  const int b = blockIdx.z, n0 = blockIdx.x * 64, c0 = blockIdx.y * 64;
  const float* xp = x + ((size_t)b * DCH + c0) * NPIX + n0;
  for (int i = 0; i < 4; i++) {
    int slot = t + i * 256;
    int c = slot >> 4, nq = (slot & 15) * 4;
    float4 v = *(const float4*)(xp + (size_t)c * NPIX + nq);
    ts[c][nq + 0] = v.x; ts[c][nq + 1] = v.y; ts[c][nq + 2] = v.z; ts[c][nq + 3] = v.w;
  }
  __syncthreads();
  for (int i = 0; i < 2; i++) {
    int slot = t + i * 256;
    int n = slot >> 3, cq = (slot & 7) * 8;
    bf16x8 pk;
    for (int j = 0; j < 8; j++) pk[j] = (bf16)ts[cq + j][n];
    *(bf16x8*)(xb + ((size_t)b * NPIX + n0 + n) * DCH + c0 + cq) = pk;
  }
}

// ============ K1: 1x1 conv as bf16 MFMA GEMM ============
__global__ __launch_bounds__(256) void conv_mfma(
    const bf16* __restrict__ xb, const bf16* __restrict__ wb,
    const float* __restrict__ bias,
    bf16* __restrict__ qb, bf16* __restrict__ kb, bf16* __restrict__ vb)
{
  __shared__ bf16 at[128 * 64];
  __shared__ bf16 bt[128 * 64];
  __shared__ float bs[128];
  const int t  = threadIdx.x;
  const int n0 = blockIdx.x * 128;
  const int o0 = blockIdx.y * 128;
  if (t < 128) bs[t] = bias[o0 + t];
  const int lane = t & 63, wave = t >> 6;
  const int wm = wave >> 1, wn = wave & 1;
  const int l15 = lane & 15, quad = lane >> 4;
  const int l7 = l15 & 7;

  floatx4 acc[4][4];
  for (int i=0;i<4;i++) for (int j=0;j<4;j++) for (int r=0;r<4;r++) acc[i][j][r] = 0.f;

  for (int k0 = 0; k0 < DCH; k0 += 64) {
    stage_tile(wb + (size_t)o0 * DCH + k0, DCH, at, t);
    stage_tile(xb + (size_t)n0 * DCH + k0, DCH, bt, t);
    __syncthreads();
    for (int kk = 0; kk < 2; kk++) {
      bf16x8 af[4], bfr[4];
      int sw = ((kk * 4 + quad) ^ l7) * 8;
      for (int f = 0; f < 4; f++)
        af[f]  = *(const bf16x8*)&at[(wm*64 + f*16 + l15)*64 + sw];
      for (int f = 0; f < 4; f++)
        bfr[f] = *(const bf16x8*)&bt[(wn*64 + f*16 + l15)*64 + sw];
      for (int fm = 0; fm < 4; fm++)
        for (int fn = 0; fn < 4; fn++)
          acc[fm][fn] = __builtin_amdgcn_mfma_f32_16x16x32_bf16(af[fm], bfr[fn], acc[fm][fn], 0, 0, 0);
    }
    __syncthreads();
  }

  const float scale = (o0 < 512) ? 0.25f : 1.0f;
  bf16* dst; int od;
  if (o0 < 256)      { dst = qb; od = o0; }
  else if (o0 < 512) { dst = kb; od = o0 - 256; }
  else               { dst = vb; od = o0 - 512; }

  for (int fm = 0; fm < 4; fm++)
    for (int fn = 0; fn < 4; fn++) {
      int o_l = wm*64 + fm*16 + quad*4;
      int n_g = n0 + wn*64 + fn*16 + l15;
      bf16x4 pk;
      for (int r = 0; r < 4; r++)
        pk[r] = (bf16)((acc[fm][fn][r] + bs[o_l + r]) * scale);
      *(bf16x4*)(dst + (size_t)n_g * DCH + od + o_l) = pk;
    }
}

// ============ K2: pass A — E = exp(q k^T); rowpart[b][m_tile][n] = partial rowsum ============
__global__ __launch_bounds__(256) void pass_a(
    const bf16* __restrict__ qb, const bf16* __restrict__ kb,
    bf16* __restrict__ E, float* __restrict__ rowpartG)
{
  __shared__ bf16 kt[128 * 64];
  __shared__ bf16 qt[128 * 64];
  __shared__ float rowpart[128];
  const int b = blockIdx.z;
  qb += (size_t)b * NPIX * DCH;
  kb += (size_t)b * NPIX * DCH;
  E  += (size_t)b * NPIX * NPIX;
  float* rp = rowpartG + ((size_t)b * 32 + blockIdx.x) * NPIX;
  const int t  = threadIdx.x;
  const int m0 = blockIdx.x * 128;
  const int n0 = blockIdx.y * 128;
  const int lane = t & 63, wave = t >> 6;
  const int wm = wave >> 1, wn = wave & 1;
  const int l15 = lane & 15, quad = lane >> 4;
  const int l7 = l15 & 7;

  floatx4 acc[4][4];
  for (int i=0;i<4;i++) for (int j=0;j<4;j++) for (int r=0;r<4;r++) acc[i][j][r] = 0.f;

  for (int k0 = 0; k0 < DCH; k0 += 64) {
    stage_tile(kb + (size_t)m0 * DCH + k0, DCH, kt, t);
    stage_tile(qb + (size_t)n0 * DCH + k0, DCH, qt, t);
    __syncthreads();
    for (int kk = 0; kk < 2; kk++) {
      bf16x8 af[4], bfr[4];
      int sw = ((kk * 4 + quad) ^ l7) * 8;
      for (int f = 0; f < 4; f++)
        af[f]  = *(const bf16x8*)&kt[(wm*64 + f*16 + l15)*64 + sw];
      for (int f = 0; f < 4; f++)
        bfr[f] = *(const bf16x8*)&qt[(wn*64 + f*16 + l15)*64 + sw];
      for (int fm = 0; fm < 4; fm++)
        for (int fn = 0; fn < 4; fn++)
          acc[fm][fn] = __builtin_amdgcn_mfma_f32_16x16x32_bf16(af[fm], bfr[fn], acc[fm][fn], 0, 0, 0);
    }
    __syncthreads();
  }

  if (t < 128) rowpart[t] = 0.f;
  __syncthreads();

  float rsum[4] = {0.f, 0.f, 0.f, 0.f};
  for (int fm = 0; fm < 4; fm++)
    for (int fn = 0; fn < 4; fn++) {
      int n_g = n0 + wn*64 + fn*16 + l15;
      int m_g = m0 + wm*64 + fm*16 + quad*4;
      bf16x4 pk;
      float s = 0.f;
      for (int r = 0; r < 4; r++) {
        float e = __expf(acc[fm][fn][r]);
        pk[r] = (bf16)e;
        s += e;
      }
      *(bf16x4*)(E + (size_t)n_g * NPIX + m_g) = pk;
      rsum[fn] += s;
    }
  for (int fn = 0; fn < 4; fn++) {
    float s = rsum[fn];
    s += __shfl_xor(s, 16);
    s += __shfl_xor(s, 32);
    if (quad == 0) atomicAdd(&rowpart[wn*64 + fn*16 + l15], s);  // LDS atomic (wm merge only)
  }
  __syncthreads();
  if (t < 128) rp[n0 + t] = rowpart[t];   // deterministic partial store
}

// ============ K3: colpart[b][ng][m] = sum over 128-row group of exp(u_n)*E[n][m] ============
__global__ __launch_bounds__(256) void col_pass(
    const bf16* __restrict__ E, const float* __restrict__ rowpartG,
    float* __restrict__ colpartG, float logm)
{
  __shared__ float eus[128];
  const int b = blockIdx.z;
  E += (size_t)b * NPIX * NPIX;
  const float* rp = rowpartG + (size_t)b * 32 * NPIX;
  float* cp = colpartG + ((size_t)b * 32 + blockIdx.y) * NPIX;
  const int t = threadIdx.x;
  const int col = blockIdx.x * 1024 + t * 4;
  const int nbase = blockIdx.y * 128;
  if (t < 128) {
    float s = 0.f;
    for (int mi = 0; mi < 32; mi++) s += rp[(size_t)mi * NPIX + nbase + t];
    eus[t] = __expf(logm - __logf(s));
  }
  __syncthreads();
  float a0 = 0.f, a1 = 0.f, a2 = 0.f, a3 = 0.f;
  for (int r = 0; r < 128; r++) {
    float eu = eus[r];
    bf16x4 ev = *(const bf16x4*)(E + (size_t)(nbase + r) * NPIX + col);
    a0 += eu * (float)ev[0];
    a1 += eu * (float)ev[1];
    a2 += eu * (float)ev[2];
    a3 += eu * (float)ev[3];
  }
  float4 o = {a0, a1, a2, a3};
  *(float4*)(cp + col) = o;
}

// ============ K4: v''T[d][m] = exp(vpot[m]) * v[m][d] ============
__global__ __launch_bounds__(256) void vpp_kernel(
    const bf16* __restrict__ vb, const float* __restrict__ colpartG,
    bf16* __restrict__ vppT, float logm)
{
  __shared__ float ts[64][65];
  __shared__ float ef[64];
  const int b = blockIdx.z;
  vb += (size_t)b * NPIX * DCH;
  const float* cp = colpartG + (size_t)b * 32 * NPIX;
  vppT += (size_t)b * DCH * NPIX;
  const int t = threadIdx.x;
  const int m0 = blockIdx.x * 64, d0 = blockIdx.y * 64;
  if (t < 64) {
    float s = 0.f;
    for (int g = 0; g < 32; g++) s += cp[(size_t)g * NPIX + m0 + t];
    ef[t] = __expf(logm - __logf(s));
  }
  __syncthreads();
  for (int i = 0; i < 2; i++) {
    int slot = t + i * 256;
    int m = slot >> 3, dq = (slot & 7) * 8;
    bf16x8 v = *(const bf16x8*)(vb + (size_t)(m0 + m) * DCH + d0 + dq);
    float s = ef[m];
    for (int j = 0; j < 8; j++) ts[dq + j][m] = s * (float)v[j];
  }
  __syncthreads();
  for (int i = 0; i < 2; i++) {
    int slot = t + i * 256;
    int d = slot >> 3, mq = (slot & 7) * 8;
    bf16x8 pk;
    for (int j = 0; j < 8; j++) pk[j] = (bf16)ts[d][mq + j];
    *(bf16x8*)(vppT + (size_t)(d0 + d) * NPIX + m0 + mq) = pk;
  }
}

// ============ K5: pass C — part[b][kc][d][n] = bf16( exp(u[n]) * (E_chunk @ v'')[n][d] ) ============
__global__ __launch_bounds__(256) void pass_c(
    const bf16* __restrict__ E, const bf16* __restrict__ vppT,
    const float* __restrict__ rowpartG, bf16* __restrict__ part, float logm)
{
  __shared__ bf16 et[128 * 64];
  __shared__ bf16 vt[128 * 64];
  __shared__ float eus[128];
  const int z = blockIdx.z;
  const int b = z >> 2, kc = z & 3;
  E += (size_t)b * NPIX * NPIX;
  vppT += (size_t)b * DCH * NPIX;
  const float* rp = rowpartG + (size_t)b * 32 * NPIX;
  part += (size_t)(b * 4 + kc) * DCH * NPIX;
  const int t  = threadIdx.x;
  const int n0 = blockIdx.x * 128;
  const int d0 = blockIdx.y * 128;
  const int mstart = kc * 1024;
  if (t < 128) {
    float s = 0.f;
    for (int mi = 0; mi < 32; mi++) s += rp[(size_t)mi * NPIX + n0 + t];
    eus[t] = __expf(logm - __logf(s));
  }
  const int lane = t & 63, wave = t >> 6;
  const int wn = wave >> 1, wd = wave & 1;
  const int l15 = lane & 15, quad = lane >> 4;
  const int l7 = l15 & 7;

  floatx4 acc[4][4];
  for (int i=0;i<4;i++) for (int j=0;j<4;j++) for (int r=0;r<4;r++) acc[i][j][r] = 0.f;
  __syncthreads();

  for (int k0 = mstart; k0 < mstart + 1024; k0 += 64) {
    stage_tile(E + (size_t)n0 * NPIX + k0, NPIX, et, t);
    stage_tile(vppT + (size_t)d0 * NPIX + k0, NPIX, vt, t);
    __syncthreads();
    for (int kk = 0; kk < 2; kk++) {
      bf16x8 af[4], bfr[4];
      int sw = ((kk * 4 + quad) ^ l7) * 8;
      for (int f = 0; f < 4; f++)
        af[f]  = *(const bf16x8*)&et[(wn*64 + f*16 + l15)*64 + sw];
      for (int f = 0; f < 4; f++)
        bfr[f] = *(const bf16x8*)&vt[(wd*64 + f*16 + l15)*64 + sw];
      for (int fn = 0; fn < 4; fn++)
        for (int fd = 0; fd < 4; fd++)
          acc[fn][fd] = __builtin_amdgcn_mfma_f32_16x16x32_bf16(af[fn], bfr[fd], acc[fn][fd], 0, 0, 0);
    }
    __syncthreads();
  }

  for (int fn = 0; fn < 4; fn++)
    for (int fd = 0; fd < 4; fd++) {
      int d_g = d0 + wd*64 + fd*16 + l15;
      int n_l = wn*64 + fn*16 + quad*4;
      bf16x4 o;
      o[0] = (bf16)(acc[fn][fd][0] * eus[n_l + 0]);
      o[1] = (bf16)(acc[fn][fd][1] * eus[n_l + 1]);
      o[2] = (bf16)(acc[fn][fd][2] * eus[n_l + 2]);
      o[3] = (bf16)(acc[fn][fd][3] * eus[n_l + 3]);
      *(bf16x4*)(part + (size_t)d_g * NPIX + n0 + n_l) = o;
    }
}

// ============ K6: reduce split-K partials (both batches), bf16 -> f32 ============
__global__ __launch_bounds__(256) void reduce_k(
    const bf16* __restrict__ part, float* __restrict__ outp)
{
  size_t i4 = ((size_t)blockIdx.x * 256 + threadIdx.x) * 4;
  size_t b = i4 >> 20;
  size_t off = i4 & (size_t)1048575;
  const bf16* p = part + b * 4 * (size_t)1048576 + off;
  bf16x4 a = *(const bf16x4*)(p);
  bf16x4 bq = *(const bf16x4*)(p + (size_t)1048576);
  bf16x4 c = *(const bf16x4*)(p + (size_t)2097152);
  bf16x4 d = *(const bf16x4*)(p + (size_t)3145728);
  float4 s = { (float)a[0]+(float)bq[0]+(float)c[0]+(float)d[0],
               (float)a[1]+(float)bq[1]+(float)c[1]+(float)d[1],
               (float)a[2]+(float)bq[2]+(float)c[2]+(float)d[2],
               (float)a[3]+(float)bq[3]+(float)c[3]+(float)d[3] };
  *(float4*)(outp + i4) = s;
}

extern "C" void kernel_launch(void* const* d_in, const int* in_sizes, int n_in,
                              void* d_out, int out_size, void* d_ws, size_t ws_size,
                              hipStream_t stream) {
  (void)in_sizes; (void)n_in; (void)out_size; (void)ws_size;
  const float* x    = (const float*)d_in[0];
  const float* Wm   = (const float*)d_in[1];
  const float* bias = (const float*)d_in[2];
  float* outp = (float*)d_out;
  char* ws = (char*)d_ws;

  bf16*  xb   = (bf16*)(ws + OFF_XB);
  bf16*  wb   = (bf16*)(ws + OFF_WB);
  bf16*  qb   = (bf16*)(ws + OFF_Q);
  bf16*  kb   = (bf16*)(ws + OFF_K);
  bf16*  vb   = (bf16*)(ws + OFF_V);
  bf16*  E    = (bf16*)(ws + OFF_E);
  bf16*  vppT = (bf16*)(ws + OFF_VPP);
  float* rp   = (float*)(ws + OFF_RP);
  float* cp   = (float*)(ws + OFF_CP);
  bf16*  part = (bf16*)(ws + OFF_PART);

  const float logm = logf(1.0f / 4096.0f + 1e-8f);

  prep<<<dim3(64, 5, 2), 256, 0, stream>>>(x, Wm, xb, wb);
  conv_mfma<<<dim3(64, 6), 256, 0, stream>>>(xb, wb, bias, qb, kb, vb);

  pass_a<<<dim3(32, 32, 2), 256, 0, stream>>>(qb, kb, E, rp);
  col_pass<<<dim3(4, 32, 2), 256, 0, stream>>>(E, rp, cp, logm);
  vpp_kernel<<<dim3(64, 4, 2), 256, 0, stream>>>(vb, cp, vppT, logm);
  pass_c<<<dim3(32, 2, 8), 256, 0, stream>>>(E, vppT, rp, part, logm);
  reduce_k<<<2048, 256, 0, stream>>>(part, outp);
}